// Round 7
// baseline (85.713 us; speedup 1.0000x reference)
//
#include <hip/hip_runtime.h>
#include <hip/hip_bf16.h>

// Scaled dot-product attention, B=16, S=2048, D=128, fp32 in/out.
//  prep_kv: K,V -> bf16 once; per-KVBLK=32-tile pre-swizzled LDS images in d_ws.
//  sdpa_fwd: 32x32 MFMA flash attention, 1024 threads = 4 q-groups x 4
//  KV-quarters (H=4 split-KV -> 4 waves/SIMD), swapped QK^T, in-register
//  softmax (cvt_pk + shfl_xor(32)), linear global_load_lds double-buffered
//  staging, 3-round online-softmax merge of the quarters through LDS.

#define NB 16
#define NS 2048
#define ND 128
#define KVB 32
#define NTT (NS / KVB)           // 64 tiles per batch
#define NTQ (NTT / 4)            // 16 tiles per quarter
#define IMG 16384                // per-tile image: K 8KB + V 8KB
// Q pre-scale: (1/sqrt(128)) * log2(e)  -> softmax in exp2 domain
#define QSC (0.08838834764831845f * 1.4426950408889634f)

typedef __attribute__((ext_vector_type(8))) short bf16x8;
typedef __attribute__((ext_vector_type(4))) short short4v;
typedef __attribute__((ext_vector_type(16))) float f32x16;
typedef __attribute__((ext_vector_type(4))) int int4v;

__device__ __forceinline__ short f2bf(float f) {
    unsigned u = __builtin_bit_cast(unsigned, f);
    return (short)((u + 0x7fffu + ((u >> 16) & 1u)) >> 16);  // RNE
}

#if __has_builtin(__builtin_amdgcn_exp2f)
#define EXP2F(x) __builtin_amdgcn_exp2f(x)
#else
#define EXP2F(x) __expf((x) * 0.6931471805599453f)
#endif

__device__ __forceinline__ void gll16(const void* g, void* l) {
    __builtin_amdgcn_global_load_lds(
        (const __attribute__((address_space(1))) uint32_t*)g,
        (__attribute__((address_space(3))) uint32_t*)l, 16, 0, 0);
}

// ---------------- pre-pass: build swizzled bf16 tile images ----------------
// Each block converts 64 KV rows = two 32-row images.
// K image: (r', d) at byte r'*256 + ((2d) ^ ((r'&7)<<4))           [8KB]
// V image: (kk=r', d) at byte 8192 + d*64 + ((2r') ^ (((d>>1)&3)<<4)) [8KB]
__global__ __launch_bounds__(256, 2)
void prep_kv(const float* __restrict__ Kg, const float* __restrict__ Vg,
             uint8_t* __restrict__ ws) {
    __shared__ __align__(16) uint8_t img[2 * IMG];
    const int tid = threadIdx.x;
    const int t = blockIdx.x, b = blockIdx.y;
    const float* Kb = Kg + ((size_t)b * NS + (size_t)t * 64) * ND;
    const float* Vb = Vg + ((size_t)b * NS + (size_t)t * 64) * ND;
#pragma unroll
    for (int it = 0; it < 8; ++it) {
        int idx = it * 256 + tid;
        int r  = idx >> 5;            // kv row 0..63
        int c4 = (idx & 31) << 2;     // d 0..124 step 4
        int sub = (r >> 5) * (2 * 8192);  // which 32-row image
        int rr = r & 31;
        float4 kvv = *(const float4*)(Kb + (size_t)r * ND + c4);
        short4v ks = { f2bf(kvv.x), f2bf(kvv.y), f2bf(kvv.z), f2bf(kvv.w) };
        *(short4v*)&img[sub + rr * 256 + ((c4 * 2) ^ ((rr & 7) << 4))] = ks;
        float4 vv = *(const float4*)(Vb + (size_t)r * ND + c4);
        float vf[4] = { vv.x, vv.y, vv.z, vv.w };
#pragma unroll
        for (int di = 0; di < 4; ++di) {
            int d = c4 + di;
            *(short*)&img[sub + 8192 + d * 64 + ((rr * 2) ^ (((d >> 1) & 3) << 4))]
                = f2bf(vf[di]);
        }
    }
    __syncthreads();
    float4* dst = (float4*)(ws + (size_t)(b * (NTT / 2) + t) * (2 * IMG));
    const float4* srcl = (const float4*)img;
#pragma unroll
    for (int j = 0; j < 8; ++j)
        dst[j * 256 + tid] = srcl[j * 256 + tid];
}

// ---------------- main attention kernel ----------------
__global__ __launch_bounds__(1024, 4)
void sdpa_fwd(const float* __restrict__ Qg, const uint8_t* __restrict__ ws,
              float* __restrict__ Og) {
    // [buf][kv-quarter] double-buffered tile images: 128 KB
    __shared__ __align__(16) uint8_t kv[2][4][IMG];

    const int tid  = threadIdx.x;
    const int w    = tid >> 6;        // 0..15
    const int wq   = w & 3;           // q-group 0..3
    const int wh   = w >> 2;          // KV quarter 0..3
    const int lane = tid & 63;
    const int lr_  = lane & 31;       // q-col (QK) / d-col (PV) index
    const int hi   = lane >> 5;

    // block remap: same-batch blocks land on the same XCD (gid%8 constant)
    const int gid  = blockIdx.x;                     // 0..255
    const int b    = (gid & 7) * 2 + ((gid >> 3) & 1);
    const int qblk = gid >> 4;                       // 0..15
    const int q0w  = qblk * 128 + wq * 32;

    // Q fragments: qf[dc] = Q[q0w + lr_][dc*16 + hi*8 + 0..7] * QSC
    bf16x8 qf[8];
    {
        const float* qrow = Qg + ((size_t)b * NS + q0w + lr_) * ND;
#pragma unroll
        for (int dc = 0; dc < 8; ++dc) {
            const float4* p = (const float4*)(qrow + dc * 16 + hi * 8);
            float4 x0 = p[0], x1 = p[1];
            bf16x8 f;
            f[0] = f2bf(x0.x * QSC); f[1] = f2bf(x0.y * QSC);
            f[2] = f2bf(x0.z * QSC); f[3] = f2bf(x0.w * QSC);
            f[4] = f2bf(x1.x * QSC); f[5] = f2bf(x1.y * QSC);
            f[6] = f2bf(x1.z * QSC); f[7] = f2bf(x1.w * QSC);
            qf[dc] = f;
        }
    }

    f32x16 acc[4];
#pragma unroll
    for (int n = 0; n < 4; ++n)
#pragma unroll
        for (int r = 0; r < 16; ++r) acc[n][r] = 0.f;
    float m_run = -__builtin_inff();
    float l_run = 0.f;

    const uint8_t* wsb = ws + (size_t)b * NTT * IMG;

    // stage tile (wh*NTQ + it) into kv[bfi][wh]; 4 q-waves x 4KB each
    auto stage = [&](int bfi, int it) {
        const uint8_t* src = wsb + (size_t)(wh * NTQ + it) * IMG
                                 + (size_t)(wq * 4096 + lane * 16);
        uint8_t* dst = &kv[bfi][wh][wq * 4096];
#pragma unroll
        for (int i = 0; i < 4; ++i)
            gll16(src + i * 1024, dst + i * 1024);
    };

    // per-lane LDS addresses (XOR-swizzled column part lives in low bits)
    const int kbase = lr_ * 256 + ((hi * 16) ^ ((lr_ & 7) << 4));
    const int vbase = 8192 + lr_ * 64 + ((hi * 16) ^ (((lr_ >> 1) & 3) << 4));

    int buf = 0;
    stage(0, 0);
    __syncthreads();

    for (int t = 0; t < NTQ; ++t) {
        if (t + 1 < NTQ) stage(buf ^ 1, t + 1);   // async prefetch next tile

        const uint8_t* img = kv[buf][wh];

        // ---- S^T = K * Q^T : one kk-block of 32, 8 d-chunks of 16 ----
        f32x16 s0;
#pragma unroll
        for (int r = 0; r < 16; ++r) s0[r] = 0.f;
        __builtin_amdgcn_s_setprio(1);
#pragma unroll
        for (int dc = 0; dc < 8; ++dc) {
            bf16x8 k0 = *(const bf16x8*)(img + (kbase ^ (dc * 32)));
            s0 = __builtin_amdgcn_mfma_f32_32x32x16_bf16(k0, qf[dc], s0, 0, 0, 0);
        }
        __builtin_amdgcn_s_setprio(0);

        // ---- in-register online softmax (exp2 domain) ----
        // lane holds P[q=lr_][k = (r&3) + 8*(r>>2) + 4*hi]
        float tmax = -__builtin_inff();
#pragma unroll
        for (int r = 0; r < 16; ++r) tmax = fmaxf(tmax, s0[r]);
        float tm = fmaxf(tmax, __shfl_xor(tmax, 32));

        if (__any(tm > m_run + 8.0f)) {          // defer-max (T13)
            float m_new = fmaxf(m_run, tm);
            float alpha = EXP2F(m_run - m_new);
            m_run = m_new;
            l_run *= alpha;
#pragma unroll
            for (int r = 0; r < 16; ++r) {
                float a = __shfl(alpha, (r & 3) + 8 * (r >> 2) + 4 * hi);
#pragma unroll
                for (int n = 0; n < 4; ++n) acc[n][r] *= a;
            }
        }

        float ts = 0.f;
#pragma unroll
        for (int r = 0; r < 16; ++r) {
            s0[r] = EXP2F(s0[r] - m_run);
            ts += s0[r];
        }
        l_run += ts + __shfl_xor(ts, 32);

        // ---- P -> bf16 A-fragments: 8 cvt_pk + shfl_xor(32) relayout ----
        int W[8];
#define PK(dst, x, y) asm("v_cvt_pk_bf16_f32 %0, %1, %2" : "=v"(dst) : "v"(x), "v"(y))
        PK(W[0], s0[0],  s0[1]);  PK(W[1], s0[2],  s0[3]);
        PK(W[2], s0[4],  s0[5]);  PK(W[3], s0[6],  s0[7]);
        PK(W[4], s0[8],  s0[9]);  PK(W[5], s0[10], s0[11]);
        PK(W[6], s0[12], s0[13]); PK(W[7], s0[14], s0[15]);
#undef PK
        bf16x8 pa[2];
#pragma unroll
        for (int g = 0; g < 2; ++g) {   // pa[g] covers k in [16g, 16g+16)
            int W0 = W[g * 4 + 0], W1 = W[g * 4 + 1];
            int W2 = W[g * 4 + 2], W3 = W[g * 4 + 3];
            int X0 = __shfl_xor(W0, 32), X1 = __shfl_xor(W1, 32);
            int X2 = __shfl_xor(W2, 32), X3 = __shfl_xor(W3, 32);
            int4v A;
            A[0] = hi ? X2 : W0;   // k = 16g + 8hi + {0,1}
            A[1] = hi ? X3 : W1;   // k = 16g + 8hi + {2,3}
            A[2] = hi ? W2 : X0;   // k = 16g + 8hi + {4,5}
            A[3] = hi ? W3 : X1;   // k = 16g + 8hi + {6,7}
            pa[g] = __builtin_bit_cast(bf16x8, A);
        }

        // ---- O += P * V : 4 d-blocks of 32, 2 k-chunks of 16 ----
        __builtin_amdgcn_s_setprio(1);
#pragma unroll
        for (int n = 0; n < 4; ++n) {
#pragma unroll
            for (int kc = 0; kc < 2; ++kc) {
                bf16x8 vf = *(const bf16x8*)(img + ((vbase ^ (kc * 32)) + n * 2048));
                acc[n] = __builtin_amdgcn_mfma_f32_32x32x16_bf16(pa[kc], vf, acc[n], 0, 0, 0);
            }
        }
        __builtin_amdgcn_s_setprio(0);

        __syncthreads();   // next tile's images now resident (all quarters)
        buf ^= 1;
    }

    // ---- merge the 4 KV quarters (sequential online-softmax combine) ----
    // scr region: per q-group wq, 64 lanes x 66 f32 (stride 66 -> 2-way banks)
    float* scr = (float*)&kv[0][0][0];
    const int sbase = wq * 4224 + lane * 66;
#pragma unroll
    for (int rnd = 1; rnd <= 3; ++rnd) {
        __syncthreads();
        if (wh == rnd) {
#pragma unroll
            for (int n = 0; n < 4; ++n)
#pragma unroll
                for (int r = 0; r < 16; ++r) scr[sbase + n * 16 + r] = acc[n][r];
            scr[sbase + 64] = m_run;
            scr[sbase + 65] = l_run;
        }
        __syncthreads();
        if (wh == 0) {
            float m1 = scr[sbase + 64], l1 = scr[sbase + 65];
            float mm = fmaxf(m_run, m1);
            float a0 = EXP2F(m_run - mm), a1 = EXP2F(m1 - mm);
            l_run = l_run * a0 + l1 * a1;
            m_run = mm;
#pragma unroll
            for (int r = 0; r < 16; ++r) {
                int row = (r & 3) + 8 * (r >> 2) + 4 * hi;
                float f0 = __shfl(a0, row), f1 = __shfl(a1, row);
#pragma unroll
                for (int n = 0; n < 4; ++n)
                    acc[n][r] = acc[n][r] * f0 + scr[sbase + n * 16 + r] * f1;
            }
        }
    }

    // ---- epilogue: normalize and store fp32 (q-owner waves only) ----
    if (wh == 0) {
        float* ob = Og + ((size_t)b * NS + q0w) * ND + lr_;
#pragma unroll
        for (int r = 0; r < 16; ++r) {
            int row = (r & 3) + 8 * (r >> 2) + 4 * hi;
            float li = 1.f / __shfl(l_run, row);
#pragma unroll
            for (int n = 0; n < 4; ++n)
                ob[(size_t)row * ND + n * 32] = acc[n][r] * li;
        }
    }
}

extern "C" void kernel_launch(void* const* d_in, const int* in_sizes, int n_in,
                              void* d_out, int out_size, void* d_ws, size_t ws_size,
                              hipStream_t stream) {
    const float* Q = (const float*)d_in[0];
    const float* K = (const float*)d_in[1];
    const float* V = (const float*)d_in[2];
    float* O = (float*)d_out;
    (void)in_sizes; (void)n_in; (void)out_size; (void)ws_size;
    uint8_t* ws = (uint8_t*)d_ws;
    prep_kv<<<dim3(NS / 64, NB), 256, 0, stream>>>(K, V, ws);
    sdpa_fwd<<<dim3(NB * NS / 128, 1), 1024, 0, stream>>>(Q, ws, O);
}

// Round 8
// 64.357 us; speedup vs baseline: 1.3318x; 1.3318x over previous
//
#include <hip/hip_runtime.h>
#include <hip/hip_bf16.h>

// Scaled dot-product attention, B=16, S=2048, D=128, fp32 in/out.
//  prep_kv: K,V -> bf16 once; per-KVB=32-tile pre-swizzled LDS images in d_ws.
//  sdpa_fwd: 32x32 MFMA flash attention, 768 threads = 4 q-groups x 3
//  KV-thirds (H=3 -> 3 waves/SIMD, VGPR budget 170 so no spill), swapped
//  QK^T, in-register softmax (cvt_pk + shfl_xor(32)), linear global_load_lds
//  double-buffered staging, 2-round online-softmax merge through LDS.

#define NB 16
#define NS 2048
#define ND 128
#define KVB 32
#define NTT (NS / KVB)           // 64 tiles per batch
#define IMG 16384                // per-tile image: K 8KB + V 8KB
// Q pre-scale: (1/sqrt(128)) * log2(e)  -> softmax in exp2 domain
#define QSC (0.08838834764831845f * 1.4426950408889634f)

typedef __attribute__((ext_vector_type(8))) short bf16x8;
typedef __attribute__((ext_vector_type(4))) short short4v;
typedef __attribute__((ext_vector_type(16))) float f32x16;
typedef __attribute__((ext_vector_type(4))) int int4v;

__device__ __forceinline__ short f2bf(float f) {
    unsigned u = __builtin_bit_cast(unsigned, f);
    return (short)((u + 0x7fffu + ((u >> 16) & 1u)) >> 16);  // RNE
}

#if __has_builtin(__builtin_amdgcn_exp2f)
#define EXP2F(x) __builtin_amdgcn_exp2f(x)
#else
#define EXP2F(x) __expf((x) * 0.6931471805599453f)
#endif

__device__ __forceinline__ void gll16(const void* g, void* l) {
    __builtin_amdgcn_global_load_lds(
        (const __attribute__((address_space(1))) uint32_t*)g,
        (__attribute__((address_space(3))) uint32_t*)l, 16, 0, 0);
}

// ---------------- pre-pass: build swizzled bf16 tile images ----------------
// Each block converts 64 KV rows = two 32-row images.
// K image: (r', d) at byte r'*256 + ((2d) ^ ((r'&7)<<4))              [8KB]
// V image: (kk=r', d) at byte 8192 + d*64 + ((2r') ^ (((d>>1)&3)<<4)) [8KB]
__global__ __launch_bounds__(256, 2)
void prep_kv(const float* __restrict__ Kg, const float* __restrict__ Vg,
             uint8_t* __restrict__ ws) {
    __shared__ __align__(16) uint8_t img[2 * IMG];
    const int tid = threadIdx.x;
    const int t = blockIdx.x, b = blockIdx.y;
    const float* Kb = Kg + ((size_t)b * NS + (size_t)t * 64) * ND;
    const float* Vb = Vg + ((size_t)b * NS + (size_t)t * 64) * ND;
#pragma unroll
    for (int it = 0; it < 8; ++it) {
        int idx = it * 256 + tid;
        int r  = idx >> 5;            // kv row 0..63
        int c4 = (idx & 31) << 2;     // d 0..124 step 4
        int sub = (r >> 5) * (2 * 8192);  // which 32-row image
        int rr = r & 31;
        float4 kvv = *(const float4*)(Kb + (size_t)r * ND + c4);
        short4v ks = { f2bf(kvv.x), f2bf(kvv.y), f2bf(kvv.z), f2bf(kvv.w) };
        *(short4v*)&img[sub + rr * 256 + ((c4 * 2) ^ ((rr & 7) << 4))] = ks;
        float4 vv = *(const float4*)(Vb + (size_t)r * ND + c4);
        float vf[4] = { vv.x, vv.y, vv.z, vv.w };
#pragma unroll
        for (int di = 0; di < 4; ++di) {
            int d = c4 + di;
            *(short*)&img[sub + 8192 + d * 64 + ((rr * 2) ^ (((d >> 1) & 3) << 4))]
                = f2bf(vf[di]);
        }
    }
    __syncthreads();
    float4* dst = (float4*)(ws + (size_t)(b * (NTT / 2) + t) * (2 * IMG));
    const float4* srcl = (const float4*)img;
#pragma unroll
    for (int j = 0; j < 8; ++j)
        dst[j * 256 + tid] = srcl[j * 256 + tid];
}

// ---------------- main attention kernel ----------------
__global__ __launch_bounds__(768, 3)
void sdpa_fwd(const float* __restrict__ Qg, const uint8_t* __restrict__ ws,
              float* __restrict__ Og) {
    // [buf][kv-third] double-buffered tile images: 96 KB
    __shared__ __align__(16) uint8_t kv[2][3][IMG];

    const int tid  = threadIdx.x;
    const int w    = tid >> 6;        // 0..11
    const int wq   = w & 3;           // q-group 0..3
    const int wh   = w >> 2;          // KV third 0..2
    const int lane = tid & 63;
    const int lr_  = lane & 31;       // q-col (QK) / d-col (PV) index
    const int hi   = lane >> 5;

    // this third's tile range: 64 = 22 + 21 + 21
    const int tlo  = (wh == 0) ? 0 : (22 + 21 * (wh - 1));
    const int tcnt = (wh == 0) ? 22 : 21;

    // block remap: same-batch blocks land on the same XCD (gid%8 constant)
    const int gid  = blockIdx.x;                     // 0..255
    const int b    = (gid & 7) * 2 + ((gid >> 3) & 1);
    const int qblk = gid >> 4;                       // 0..15
    const int q0w  = qblk * 128 + wq * 32;

    // Q fragments: qf[dc] = Q[q0w + lr_][dc*16 + hi*8 + 0..7] * QSC
    bf16x8 qf[8];
    {
        const float* qrow = Qg + ((size_t)b * NS + q0w + lr_) * ND;
#pragma unroll
        for (int dc = 0; dc < 8; ++dc) {
            const float4* p = (const float4*)(qrow + dc * 16 + hi * 8);
            float4 x0 = p[0], x1 = p[1];
            bf16x8 f;
            f[0] = f2bf(x0.x * QSC); f[1] = f2bf(x0.y * QSC);
            f[2] = f2bf(x0.z * QSC); f[3] = f2bf(x0.w * QSC);
            f[4] = f2bf(x1.x * QSC); f[5] = f2bf(x1.y * QSC);
            f[6] = f2bf(x1.z * QSC); f[7] = f2bf(x1.w * QSC);
            qf[dc] = f;
        }
    }

    f32x16 acc[4];
#pragma unroll
    for (int n = 0; n < 4; ++n)
#pragma unroll
        for (int r = 0; r < 16; ++r) acc[n][r] = 0.f;
    float m_run = -__builtin_inff();
    float l_run = 0.f;

    const uint8_t* wsb = ws + (size_t)b * NTT * IMG;

    // stage tile (tlo + it) into kv[bfi][wh]; 4 q-waves x 4KB each
    auto stage = [&](int bfi, int it) {
        const uint8_t* src = wsb + (size_t)(tlo + it) * IMG
                                 + (size_t)(wq * 4096 + lane * 16);
        uint8_t* dst = &kv[bfi][wh][wq * 4096];
#pragma unroll
        for (int i = 0; i < 4; ++i)
            gll16(src + i * 1024, dst + i * 1024);
    };

    // per-lane LDS addresses (XOR-swizzled column part lives in low bits)
    const int kbase = lr_ * 256 + ((hi * 16) ^ ((lr_ & 7) << 4));
    const int vbase = 8192 + lr_ * 64 + ((hi * 16) ^ (((lr_ >> 1) & 3) << 4));

    int buf = 0;
    stage(0, 0);
    __syncthreads();

    for (int t = 0; t < 22; ++t) {
        if (t + 1 < tcnt) stage(buf ^ 1, t + 1);   // async prefetch next tile

        if (t < tcnt) {
            const uint8_t* img = kv[buf][wh];

            // ---- S^T = K * Q^T : one kk-block of 32, 8 d-chunks of 16 ----
            f32x16 s0;
#pragma unroll
            for (int r = 0; r < 16; ++r) s0[r] = 0.f;
            __builtin_amdgcn_s_setprio(1);
#pragma unroll
            for (int dc = 0; dc < 8; ++dc) {
                bf16x8 k0 = *(const bf16x8*)(img + (kbase ^ (dc * 32)));
                s0 = __builtin_amdgcn_mfma_f32_32x32x16_bf16(k0, qf[dc], s0, 0, 0, 0);
            }
            __builtin_amdgcn_s_setprio(0);

            // ---- in-register online softmax (exp2 domain) ----
            // lane holds P[q=lr_][k = (r&3) + 8*(r>>2) + 4*hi]
            float tmax = -__builtin_inff();
#pragma unroll
            for (int r = 0; r < 16; ++r) tmax = fmaxf(tmax, s0[r]);
            float tm = fmaxf(tmax, __shfl_xor(tmax, 32));

            if (__any(tm > m_run + 8.0f)) {          // defer-max (T13)
                float m_new = fmaxf(m_run, tm);
                float alpha = EXP2F(m_run - m_new);
                m_run = m_new;
                l_run *= alpha;
#pragma unroll
                for (int r = 0; r < 16; ++r) {
                    float a = __shfl(alpha, (r & 3) + 8 * (r >> 2) + 4 * hi);
#pragma unroll
                    for (int n = 0; n < 4; ++n) acc[n][r] *= a;
                }
            }

            float ts = 0.f;
#pragma unroll
            for (int r = 0; r < 16; ++r) {
                s0[r] = EXP2F(s0[r] - m_run);
                ts += s0[r];
            }
            l_run += ts + __shfl_xor(ts, 32);

            // ---- P -> bf16 A-fragments: 8 cvt_pk + shfl_xor(32) relayout ----
            int W[8];
#define PK(dst, x, y) asm("v_cvt_pk_bf16_f32 %0, %1, %2" : "=v"(dst) : "v"(x), "v"(y))
            PK(W[0], s0[0],  s0[1]);  PK(W[1], s0[2],  s0[3]);
            PK(W[2], s0[4],  s0[5]);  PK(W[3], s0[6],  s0[7]);
            PK(W[4], s0[8],  s0[9]);  PK(W[5], s0[10], s0[11]);
            PK(W[6], s0[12], s0[13]); PK(W[7], s0[14], s0[15]);
#undef PK
            bf16x8 pa[2];
#pragma unroll
            for (int g = 0; g < 2; ++g) {   // pa[g] covers k in [16g, 16g+16)
                int W0 = W[g * 4 + 0], W1 = W[g * 4 + 1];
                int W2 = W[g * 4 + 2], W3 = W[g * 4 + 3];
                int X0 = __shfl_xor(W0, 32), X1 = __shfl_xor(W1, 32);
                int X2 = __shfl_xor(W2, 32), X3 = __shfl_xor(W3, 32);
                int4v A;
                A[0] = hi ? X2 : W0;   // k = 16g + 8hi + {0,1}
                A[1] = hi ? X3 : W1;   // k = 16g + 8hi + {2,3}
                A[2] = hi ? W2 : X0;   // k = 16g + 8hi + {4,5}
                A[3] = hi ? W3 : X1;   // k = 16g + 8hi + {6,7}
                pa[g] = __builtin_bit_cast(bf16x8, A);
            }

            // ---- O += P * V : 4 d-blocks of 32, 2 k-chunks of 16 ----
            __builtin_amdgcn_s_setprio(1);
#pragma unroll
            for (int n = 0; n < 4; ++n) {
#pragma unroll
                for (int kc = 0; kc < 2; ++kc) {
                    bf16x8 vf = *(const bf16x8*)(img + ((vbase ^ (kc * 32)) + n * 2048));
                    acc[n] = __builtin_amdgcn_mfma_f32_32x32x16_bf16(pa[kc], vf, acc[n], 0, 0, 0);
                }
            }
            __builtin_amdgcn_s_setprio(0);
        }

        __syncthreads();   // next tile's images now resident (all thirds)
        buf ^= 1;
    }

    // ---- merge the 3 KV thirds (sequential online-softmax combine) ----
    // scr region: per q-group wq, 64 lanes x 66 f32 (stride 66 -> 2-way banks)
    float* scr = (float*)&kv[0][0][0];
    const int sbase = wq * 4224 + lane * 66;
#pragma unroll
    for (int rnd = 1; rnd <= 2; ++rnd) {
        __syncthreads();
        if (wh == rnd) {
#pragma unroll
            for (int n = 0; n < 4; ++n)
#pragma unroll
                for (int r = 0; r < 16; ++r) scr[sbase + n * 16 + r] = acc[n][r];
            scr[sbase + 64] = m_run;
            scr[sbase + 65] = l_run;
        }
        __syncthreads();
        if (wh == 0) {
            float m1 = scr[sbase + 64], l1 = scr[sbase + 65];
            float mm = fmaxf(m_run, m1);
            float a0 = EXP2F(m_run - mm), a1 = EXP2F(m1 - mm);
            l_run = l_run * a0 + l1 * a1;
            m_run = mm;
#pragma unroll
            for (int r = 0; r < 16; ++r) {
                int row = (r & 3) + 8 * (r >> 2) + 4 * hi;
                float f0 = __shfl(a0, row), f1 = __shfl(a1, row);
#pragma unroll
                for (int n = 0; n < 4; ++n)
                    acc[n][r] = acc[n][r] * f0 + scr[sbase + n * 16 + r] * f1;
            }
        }
    }

    // ---- epilogue: normalize and store fp32 (q-owner waves only) ----
    if (wh == 0) {
        float* ob = Og + ((size_t)b * NS + q0w) * ND + lr_;
#pragma unroll
        for (int r = 0; r < 16; ++r) {
            int row = (r & 3) + 8 * (r >> 2) + 4 * hi;
            float li = 1.f / __shfl(l_run, row);
#pragma unroll
            for (int n = 0; n < 4; ++n)
                ob[(size_t)row * ND + n * 32] = acc[n][r] * li;
        }
    }
}

extern "C" void kernel_launch(void* const* d_in, const int* in_sizes, int n_in,
                              void* d_out, int out_size, void* d_ws, size_t ws_size,
                              hipStream_t stream) {
    const float* Q = (const float*)d_in[0];
    const float* K = (const float*)d_in[1];
    const float* V = (const float*)d_in[2];
    float* O = (float*)d_out;
    (void)in_sizes; (void)n_in; (void)out_size; (void)ws_size;
    uint8_t* ws = (uint8_t*)d_ws;
    prep_kv<<<dim3(NS / 64, NB), 256, 0, stream>>>(K, V, ws);
    sdpa_fwd<<<dim3(NB * NS / 128, 1), 768, 0, stream>>>(Q, ws, O);
}